// Round 1
// baseline (919.788 us; speedup 1.0000x reference)
//
#include <hip/hip_runtime.h>

typedef __attribute__((ext_vector_type(8))) _Float16 half8;
typedef __attribute__((ext_vector_type(4))) float f32x4;

#define MFMA16(a,b,c) __builtin_amdgcn_mfma_f32_16x16x32_f16(a, b, c, 0, 0, 0)

// ---------------- prep kernel ----------------
// ws layout:
//   wqkvT : [768][256] f16   @ 0        (393216 B)  row c = qkv output col, ordered
//           per head h: [q_h(32) | k_h(32) | v_h(32)]; SCALE folded into q part
//   wpT   : [256][256] f16   @ 393216   (131072 B)  wpT[n][k] = wp[k][n]
//   bqkv  : [768] f32        @ 524288   (3072 B)    same col order, SCALE folded
//   biasg : [8][64][64] f32  @ 527360   (131072 B)  rpb_table[rel_idx[r][c]][h]
// total 658432 B
__global__ void prep_kernel(const float* __restrict__ wq, const float* __restrict__ bq,
                            const float* __restrict__ wkv, const float* __restrict__ bkv,
                            const float* __restrict__ wp, const float* __restrict__ rpb,
                            const int* __restrict__ rel,
                            _Float16* __restrict__ wqkvT, _Float16* __restrict__ wpT,
                            float* __restrict__ bqkv, float* __restrict__ biasg)
{
    int idx = blockIdx.x * 256 + threadIdx.x;
    const float scale = 0.17677669529663687f;  // 32^-0.5
    if (idx < 196608) {
        int c = idx >> 8, k = idx & 255;
        int h = c / 96, r = c % 96;
        float v;
        if (r < 32)      v = wq[k*256 + h*32 + r] * scale;
        else if (r < 64) v = wkv[k*512 + h*32 + (r-32)];
        else             v = wkv[k*512 + 256 + h*32 + (r-64)];
        wqkvT[c*256 + k] = (_Float16)v;
    } else if (idx < 262144) {
        int i = idx - 196608;
        int n = i >> 8, k = i & 255;
        wpT[i] = (_Float16)wp[k*256 + n];
    } else if (idx < 262912) {
        int c = idx - 262144;
        int h = c / 96, r = c % 96;
        float v;
        if (r < 32)      v = bq[h*32 + r] * scale;
        else if (r < 64) v = bkv[h*32 + (r-32)];
        else             v = bkv[256 + h*32 + (r-64)];
        bqkv[c] = v;
    } else if (idx < 295680) {
        int i = idx - 262912;
        int h = i >> 12, rc = i & 4095;
        biasg[i] = rpb[rel[rc]*8 + h];
    }
}

// ---------------- main fused kernel ----------------
// 1 block = 1 window (4096 blocks), 256 threads = 4 waves.
// LDS strides: sx 264 (bank stride 4, 2-way = free), sq/sk 40 (16B-aligned rows,
// 2-way), sv/sP 72 (144B rows, 2-way), sO 40. Total 77824 B -> 2 blocks/CU.
__global__ __launch_bounds__(256, 2)
void attn_main(const float* __restrict__ x,
               const _Float16* __restrict__ wqkvT,
               const _Float16* __restrict__ wpT,
               const float* __restrict__ bqkv,
               const float* __restrict__ biasg,
               const float* __restrict__ bp,
               float* __restrict__ out)
{
    __shared__ _Float16 sx[64*264];     // x window, f16, A-layout source
    __shared__ _Float16 sq[2][64*40];   // q  [head_in_pair][token][d]
    __shared__ _Float16 sk[2][64*40];   // k  [head_in_pair][token][d]
    __shared__ _Float16 sv[2][32*72];   // v^T [head_in_pair][d][token]
    __shared__ _Float16 sP[64*72];      // softmax probs [query][key]
    __shared__ _Float16 sO[64*40];      // per-head attention out [token][d]

    const int tid  = threadIdx.x;
    const int w    = tid >> 6;
    const int lane = tid & 63;
    const int l15  = lane & 15;
    const int quad = lane >> 4;
    const int b    = blockIdx.x;

    const float* xb = x + (size_t)b * (64*256);

    // ---- stage A: x (fp32) -> LDS f16 ----
    #pragma unroll
    for (int i = 0; i < 16; ++i) {
        int c4  = i*256 + tid;          // float4 index
        int row = c4 >> 6;
        int col = (c4 & 63) << 2;
        float4 v = ((const float4*)xb)[c4];
        union { _Float16 h[4]; uint2 u2; } pk;
        pk.h[0] = (_Float16)v.x; pk.h[1] = (_Float16)v.y;
        pk.h[2] = (_Float16)v.z; pk.h[3] = (_Float16)v.w;
        *(uint2*)(&sx[row*264 + col]) = pk.u2;
    }

    // persistent out-proj accumulators: [m-tile][n-tile], cols 64*w..64*w+63
    f32x4 dacc[4][4];
    #pragma unroll
    for (int i = 0; i < 4; ++i)
        #pragma unroll
        for (int j = 0; j < 4; ++j)
            dacc[i][j] = (f32x4){0.f, 0.f, 0.f, 0.f};

    __syncthreads();

    for (int pair = 0; pair < 4; ++pair) {
        // ---- stage B: qkv = x @ Wqkv for heads 2*pair, 2*pair+1 ----
        // wave w owns output cols [w*48, w*48+48) of the pair's 192 cols.
        #pragma unroll
        for (int nt = 0; nt < 3; ++nt) {
            int seg  = w*48 + nt*16;            // 0..176, multiple of 16
            int gcol = pair*192 + seg + l15;
            f32x4 acc[4];
            acc[0] = acc[1] = acc[2] = acc[3] = (f32x4){0.f,0.f,0.f,0.f};
            const _Float16* wrow = wqkvT + (size_t)gcol*256 + quad*8;
            #pragma unroll
            for (int ks = 0; ks < 8; ++ks) {
                half8 bf = *(const half8*)(wrow + ks*32);
                #pragma unroll
                for (int mt = 0; mt < 4; ++mt) {
                    half8 af = *(const half8*)&sx[(16*mt + l15)*264 + ks*32 + quad*8];
                    acc[mt] = MFMA16(af, bf, acc[mt]);
                }
            }
            float bv = bqkv[pair*192 + seg + l15];
            int hs  = (seg >= 96) ? 1 : 0;      // head within pair
            int r   = seg - 96*hs;
            int ty  = r >> 5;                    // 0=q 1=k 2=v
            int ds_ = r & 31;                    // 0 or 16
            #pragma unroll
            for (int mt = 0; mt < 4; ++mt) {
                #pragma unroll
                for (int rg = 0; rg < 4; ++rg) {
                    _Float16 hv = (_Float16)(acc[mt][rg] + bv);
                    int token = 16*mt + quad*4 + rg;
                    if (ty == 0)      sq[hs][token*40 + ds_ + l15] = hv;
                    else if (ty == 1) sk[hs][token*40 + ds_ + l15] = hv;
                    else              sv[hs][(ds_ + l15)*72 + token] = hv;
                }
            }
        }
        __syncthreads();   // qkv visible to all waves

        for (int hh = 0; hh < 2; ++hh) {
            int h = pair*2 + hh;
            // ---- S = (q*scale) @ k^T ; wave w owns query rows 16w..16w+15 ----
            half8 aq = *(const half8*)&sq[hh][(16*w + l15)*40 + quad*8];
            f32x4 s[4];
            #pragma unroll
            for (int nt = 0; nt < 4; ++nt) {
                half8 bk = *(const half8*)&sk[hh][(16*nt + l15)*40 + quad*8];
                s[nt] = MFMA16(aq, bk, ((f32x4){0.f,0.f,0.f,0.f}));
            }
            // ---- bias + softmax (rows live in 16-lane groups: butterfly) ----
            float rinv[4];
            #pragma unroll
            for (int rg = 0; rg < 4; ++rg) {
                int row = quad*4 + rg;
                const float* bg = biasg + ((h*64) + 16*w + row)*64 + l15;
                float t0 = s[0][rg] + bg[0];
                float t1 = s[1][rg] + bg[16];
                float t2 = s[2][rg] + bg[32];
                float t3 = s[3][rg] + bg[48];
                float m = fmaxf(fmaxf(t0, t1), fmaxf(t2, t3));
                #pragma unroll
                for (int d = 1; d < 16; d <<= 1)
                    m = fmaxf(m, __shfl_xor(m, d));
                float e0 = __expf(t0 - m), e1 = __expf(t1 - m);
                float e2 = __expf(t2 - m), e3 = __expf(t3 - m);
                float sum = e0 + e1 + e2 + e3;
                #pragma unroll
                for (int d = 1; d < 16; d <<= 1)
                    sum += __shfl_xor(sum, d);
                rinv[rg] = 1.0f / sum;
                int prow = (16*w + row)*72;
                sP[prow +  0 + l15] = (_Float16)e0;
                sP[prow + 16 + l15] = (_Float16)e1;
                sP[prow + 32 + l15] = (_Float16)e2;
                sP[prow + 48 + l15] = (_Float16)e3;
            }
            // ---- O = P @ V (P rows are wave-local; no barrier needed) ----
            f32x4 o[2];
            o[0] = o[1] = (f32x4){0.f,0.f,0.f,0.f};
            #pragma unroll
            for (int ks = 0; ks < 2; ++ks) {
                half8 ap = *(const half8*)&sP[(16*w + l15)*72 + ks*32 + quad*8];
                #pragma unroll
                for (int nt = 0; nt < 2; ++nt) {
                    half8 bv_ = *(const half8*)&sv[hh][(16*nt + l15)*72 + ks*32 + quad*8];
                    o[nt] = MFMA16(ap, bv_, o[nt]);
                }
            }
            // ---- scale by 1/l, stage O for out-proj ----
            #pragma unroll
            for (int nt = 0; nt < 2; ++nt)
                #pragma unroll
                for (int rg = 0; rg < 4; ++rg)
                    sO[(16*w + quad*4 + rg)*40 + nt*16 + l15] =
                        (_Float16)(o[nt][rg] * rinv[rg]);
            __syncthreads();   // sO complete

            // ---- stage D: dacc += O_h @ wp[h*32 : h*32+32, :] ----
            #pragma unroll
            for (int nt = 0; nt < 4; ++nt) {
                half8 bw = *(const half8*)(wpT + (size_t)(64*w + 16*nt + l15)*256
                                           + h*32 + quad*8);
                #pragma unroll
                for (int mt = 0; mt < 4; ++mt) {
                    half8 ao = *(const half8*)&sO[(16*mt + l15)*40 + quad*8];
                    dacc[mt][nt] = MFMA16(ao, bw, dacc[mt][nt]);
                }
            }
            __syncthreads();   // all waves done reading sO (and sk/sv safe to reuse)
        }
    }

    // ---- epilogue: + bp, store fp32 ----
    float* ob = out + (size_t)b * (64*256);
    #pragma unroll
    for (int nt = 0; nt < 4; ++nt) {
        int col = 64*w + 16*nt + l15;
        float bpv = bp[col];
        #pragma unroll
        for (int mt = 0; mt < 4; ++mt) {
            #pragma unroll
            for (int rg = 0; rg < 4; ++rg) {
                int row = 16*mt + quad*4 + rg;
                ob[row*256 + col] = dacc[mt][nt][rg] + bpv;
            }
        }
    }
}

extern "C" void kernel_launch(void* const* d_in, const int* in_sizes, int n_in,
                              void* d_out, int out_size, void* d_ws, size_t ws_size,
                              hipStream_t stream)
{
    const float* x   = (const float*)d_in[0];
    const float* wq  = (const float*)d_in[1];
    const float* bq  = (const float*)d_in[2];
    const float* wkv = (const float*)d_in[3];
    const float* bkv = (const float*)d_in[4];
    const float* wp  = (const float*)d_in[5];
    const float* bp  = (const float*)d_in[6];
    const float* rpb = (const float*)d_in[7];
    const int*   rel = (const int*)d_in[8];

    char* ws = (char*)d_ws;
    _Float16* wqkvT = (_Float16*)(ws);
    _Float16* wpT   = (_Float16*)(ws + 393216);
    float*    bqkv  = (float*)(ws + 524288);
    float*    biasg = (float*)(ws + 527360);

    hipLaunchKernelGGL(prep_kernel, dim3(1155), dim3(256), 0, stream,
                       wq, bq, wkv, bkv, wp, rpb, rel, wqkvT, wpT, bqkv, biasg);
    hipLaunchKernelGGL(attn_main, dim3(4096), dim3(256), 0, stream,
                       x, wqkvT, wpT, bqkv, biasg, bp, (float*)d_out);
}